// Round 6
// baseline (1932.290 us; speedup 1.0000x reference)
//
#include <hip/hip_runtime.h>
#include <stdint.h>

// VectorQuantizer: bf16-MFMA screen (A-in-registers, K-split, warmup-seeded
// margin recording, double-buffered pipelined B staging) + exact fp32 rescore.
// Exact semantics (proven R2..R5): d = fl(fl(s_z_pairwise + s_w_pairwise) - 2*dot_f32),
// argmin lowest-index tie-break == global atomicMin on (encf(d)<<32)|k.

constexpr int N = 32768;
constexpr int K = 8192;
constexpr int D = 256;
constexpr int CAP = 12;
constexpr int NT = 36;                 // 4 warmup tiles + 32 recording tiles
#define MARGIN 1.0e-4f

typedef __attribute__((ext_vector_type(8))) short short8v;
typedef __attribute__((ext_vector_type(4))) float float4v;

__device__ inline short f2bf(float f) {            // RNE float->bf16
    unsigned u = __float_as_uint(f);
    unsigned r = (u + 0x7FFFu + ((u >> 16) & 1u)) >> 16;
    return (short)r;
}
__device__ inline unsigned encf(float x) {         // order-preserving f32->u32
    unsigned u = __float_as_uint(x);
    return (u & 0x80000000u) ? ~u : (u | 0x80000000u);
}
__device__ inline float decf(unsigned e) {
    unsigned u = (e & 0x80000000u) ? (e & 0x7FFFFFFFu) : ~e;
    return __uint_as_float(u);
}
__device__ inline void load_lds16(const void* g, void* l) {
    __builtin_amdgcn_global_load_lds(
        (const __attribute__((address_space(1))) void*)g,
        (__attribute__((address_space(3))) void*)l, 16, 0, 0);
}

// ---------------------------------------------- fused repack + rowsq -------
// + optional best/flags init (Z call only). Pairwise sum parallelized over
// 128 threads (row-half each) with BITWISE-IDENTICAL operation order (R2).
__global__ __launch_bounds__(256) void fuse_pack(const float* __restrict__ X,
                                                 short* __restrict__ Xf,
                                                 float* __restrict__ s_out,
                                                 unsigned long long* __restrict__ best,
                                                 unsigned char* __restrict__ flags) {
    __shared__ float raw[64][260];
    __shared__ float hres[64][2];
    const int t = threadIdx.x;
    const size_t base = (size_t)blockIdx.x * 64 * D;
#pragma unroll
    for (int it = 0; it < 16; ++it) {
        int idx = it * 256 + t;
        int r = idx >> 6, c = idx & 63;
        float4 v = ((const float4*)(X + base))[idx];
        *(float4*)&raw[r][c * 4] = v;
    }
    __syncthreads();
    if (t < 128) {                     // half-row pairwise sum (order == R2)
        const int row = t >> 1, h = t & 1;
        const float* ph = raw[row] + h * 128;
        float r8[8];
#pragma unroll
        for (int j = 0; j < 8; ++j) r8[j] = __fmul_rn(ph[j], ph[j]);
        for (int i = 8; i < 128; i += 8)
#pragma unroll
            for (int j = 0; j < 8; ++j)
                r8[j] = __fadd_rn(r8[j], __fmul_rn(ph[i + j], ph[i + j]));
        hres[row][h] = __fadd_rn(__fadd_rn(__fadd_rn(r8[0], r8[1]), __fadd_rn(r8[2], r8[3])),
                                 __fadd_rn(__fadd_rn(r8[4], r8[5]), __fadd_rn(r8[6], r8[7])));
    }
    // bf16 MFMA-fragment repack (reads raw only)
    {
        const int lane = t & 63, w = t >> 6, l4 = lane >> 4, l15 = lane & 15;
        const int row = w * 16 + l15;
#pragma unroll
        for (int s = 0; s < 8; ++s) {
            const float* src = &raw[row][s * 32 + l4 * 8];
            float4 v0 = *(const float4*)src;
            float4 v1 = *(const float4*)(src + 4);
            short8v o;
            o[0] = f2bf(v0.x); o[1] = f2bf(v0.y); o[2] = f2bf(v0.z); o[3] = f2bf(v0.w);
            o[4] = f2bf(v1.x); o[5] = f2bf(v1.y); o[6] = f2bf(v1.z); o[7] = f2bf(v1.w);
            *(short8v*)(Xf + ((size_t)(blockIdx.x * 4 + w) * 8 + s) * 512 + lane * 8) = o;
        }
    }
    __syncthreads();
    if (t < 64) {
        s_out[blockIdx.x * 64 + t] = __fadd_rn(hres[t][0], hres[t][1]);
        if (best) {                    // init best/flags for these 64 rows
            best[blockIdx.x * 64 + t] = 0xFFFFFFFFFFFFFFFFull;
            flags[blockIdx.x * 64 + t] = 0;
        }
    }
}

// ------------------------------------------------------------- screen ------
// grid 512 = 128 row-groups x 4 K-quarters. Block: 4 waves; wave w owns rows
// n0+w*64 (A frags in 128 VGPR). B: 64-col tiles, DOUBLE-BUFFERED
// global_load_lds pipeline (stage tt+1 right after barrier, compute tt).
__global__ __launch_bounds__(256, 2) void vq_screen(
    const short* __restrict__ Zf, const short* __restrict__ Wf,
    const float* __restrict__ s_w, const float* __restrict__ s_z,
    const float* __restrict__ Z, const float* __restrict__ W,
    unsigned long long* __restrict__ best, unsigned char* __restrict__ gflags)
{
    __shared__ short Bs[2][4][8][512];       // 64 KB double buffer
    __shared__ unsigned rowmax[256];         // 1 KB encoded running row max
    __shared__ unsigned ccnt[256];           // 1 KB
    __shared__ unsigned candkm[256][CAP];    // 12 KB  (encf(m)&0xFFFF0000)|k

    const int t = threadIdx.x, w = t >> 6, lane = t & 63;
    const int l4 = lane >> 4, l15 = lane & 15;
    const int q = blockIdx.x & 3, rg = blockIdx.x >> 2;
    const int n0 = rg * 256;
    const int kq0 = q * 2048;

    rowmax[t] = encf(-1e30f);
    ccnt[t] = 0u;

    short8v af[4][8];
    {
        const int R = (n0 >> 4) + w * 4;
#pragma unroll
        for (int g = 0; g < 4; ++g)
#pragma unroll
            for (int s = 0; s < 8; ++s)
                af[g][s] = *(const short8v*)(Zf + ((size_t)(R + g) * 8 + s) * 512 + lane * 8);
    }

    float maxv[16];
#pragma unroll
    for (int i = 0; i < 16; ++i) maxv[i] = -1e30f;

    // prologue: stage tile 0 into buffer 0 (wave w stages col16-group w)
    {
        const int col16 = (kq0 >> 4) + 0 * 4 + w;
        const short* gB = Wf + (size_t)col16 * 8 * 512 + lane * 8;
#pragma unroll
        for (int s = 0; s < 8; ++s)
            load_lds16(gB + s * 512, &Bs[0][w][s][0]);
    }

    for (int tt = 0; tt < NT; ++tt) {
        const int cur = tt & 1;
        __syncthreads();                     // drains own stage(tt); all waves synced
        if (tt + 1 < NT) {                   // prefetch tile tt+1 into other buffer
            const int ktn = (tt + 1 < 4) ? (tt + 1) : (tt + 1 - 4);
            const int col16 = (kq0 >> 4) + ktn * 4 + w;
            const short* gB = Wf + (size_t)col16 * 8 * 512 + lane * 8;
#pragma unroll
            for (int s = 0; s < 8; ++s)
                load_lds16(gB + s * 512, &Bs[cur ^ 1][w][s][0]);
        }

        float4v acc[4][4];
#pragma unroll
        for (int i = 0; i < 4; ++i)
#pragma unroll
            for (int j = 0; j < 4; ++j)
#pragma unroll
                for (int r = 0; r < 4; ++r) acc[i][j][r] = 0.f;

#pragma unroll
        for (int s = 0; s < 8; ++s) {
            short8v bf[4];
#pragma unroll
            for (int j = 0; j < 4; ++j)
                bf[j] = *(const short8v*)&Bs[cur][j][s][lane * 8];
#pragma unroll
            for (int i = 0; i < 4; ++i)
#pragma unroll
                for (int j = 0; j < 4; ++j)
                    acc[i][j] = __builtin_amdgcn_mfma_f32_16x16x32_bf16(af[i][s], bf[j], acc[i][j], 0, 0, 0);
        }

        if (tt < 4) {                        // warmup: seed row max only
#pragma unroll
            for (int i = 0; i < 4; ++i)
#pragma unroll
                for (int r = 0; r < 4; ++r) {
                    const int slot = i * 4 + r;
                    float mj = fmaxf(fmaxf(acc[i][0][r], acc[i][1][r]),
                                     fmaxf(acc[i][2][r], acc[i][3][r]));
                    if (mj > maxv[slot]) {
                        maxv[slot] = mj;
                        atomicMax(&rowmax[w * 64 + i * 16 + l4 * 4 + r], encf(mj));
                    }
                }
            continue;
        }

        // recording tile: refresh bound (vectorized rowmax reads), then record
        const int kt = tt - 4;
#pragma unroll
        for (int i = 0; i < 4; ++i) {
            uint4 rm = *(const uint4*)&rowmax[w * 64 + i * 16 + l4 * 4];
            maxv[i * 4 + 0] = fmaxf(maxv[i * 4 + 0], decf(rm.x));
            maxv[i * 4 + 1] = fmaxf(maxv[i * 4 + 1], decf(rm.y));
            maxv[i * 4 + 2] = fmaxf(maxv[i * 4 + 2], decf(rm.z));
            maxv[i * 4 + 3] = fmaxf(maxv[i * 4 + 3], decf(rm.w));
        }
        const int kb = kq0 + kt * 64 + l15;
#pragma unroll
        for (int i = 0; i < 4; ++i) {
#pragma unroll
            for (int r = 0; r < 4; ++r) {
                const int slot = i * 4 + r;
                const int rowL = w * 64 + i * 16 + l4 * 4 + r;
                float v0 = acc[i][0][r], v1 = acc[i][1][r];
                float v2 = acc[i][2][r], v3 = acc[i][3][r];
                float mj = fmaxf(fmaxf(v0, v1), fmaxf(v2, v3));
                if (mj > maxv[slot]) {
                    maxv[slot] = mj;
                    atomicMax(&rowmax[rowL], encf(mj));
                }
                float th = maxv[slot] - MARGIN;
                if (mj >= th) {
                    if (v0 >= th) { unsigned c = atomicAdd(&ccnt[rowL], 1u); if (c < CAP) candkm[rowL][c] = (encf(v0) & 0xFFFF0000u) | (unsigned)kb; }
                    if (v1 >= th) { unsigned c = atomicAdd(&ccnt[rowL], 1u); if (c < CAP) candkm[rowL][c] = (encf(v1) & 0xFFFF0000u) | (unsigned)(kb + 16); }
                    if (v2 >= th) { unsigned c = atomicAdd(&ccnt[rowL], 1u); if (c < CAP) candkm[rowL][c] = (encf(v2) & 0xFFFF0000u) | (unsigned)(kb + 32); }
                    if (v3 >= th) { unsigned c = atomicAdd(&ccnt[rowL], 1u); if (c < CAP) candkm[rowL][c] = (encf(v3) & 0xFFFF0000u) | (unsigned)(kb + 48); }
                }
            }
        }
    }

    __syncthreads();
    // exact fp32 rescore of non-stale survivors; submit via global atomicMin
    {
        const int n = n0 + t;
        unsigned cnt = ccnt[t];
        if (cnt > (unsigned)CAP) {
            gflags[n] = 1;                   // overflow -> full-row fallback
        } else if (cnt > 0) {
            const float thr = decf(rowmax[t]) - MARGIN;
            const float sz = s_z[n];
            const float4* zr = (const float4*)(Z + (size_t)n * D);
            float bd = 1e30f; int bk = 0x7FFFFFFF;
            for (unsigned c = 0; c < cnt; ++c) {
                const unsigned cm = candkm[t][c];
                // coarse upper bound on recorded m; skip only if surely stale
                if (decf((cm & 0xFFFF0000u) + 0x10000u) < thr) continue;
                const int k = (int)(cm & 0x1FFFu);
                const float4* wr = (const float4*)(W + (size_t)k * D);
                float ax = 0.f, ay = 0.f, az = 0.f, aw = 0.f;
                for (int qq = 0; qq < 64; ++qq) {
                    float4 zv = zr[qq], wv = wr[qq];
                    ax = fmaf(zv.x, wv.x, ax);
                    ay = fmaf(zv.y, wv.y, ay);
                    az = fmaf(zv.z, wv.z, az);
                    aw = fmaf(zv.w, wv.w, aw);
                }
                float dot = (ax + ay) + (az + aw);
                float dd = (sz + s_w[k]) - 2.0f * dot;
                if (dd < bd || (dd == bd && k < bk)) { bd = dd; bk = k; }
            }
            atomicMin(&best[n], ((unsigned long long)encf(bd) << 32) | (unsigned)bk);
        }
    }
}

// ------------------------------------------------------------ fallback -----
__global__ __launch_bounds__(256) void vq_fallback(
    const float* __restrict__ Z, const float* __restrict__ W,
    const float* __restrict__ s_z, const float* __restrict__ s_w,
    const unsigned char* __restrict__ flags, unsigned long long* __restrict__ best)
{
    __shared__ int anyf;
    const int t = threadIdx.x;
    const int rbase = blockIdx.x * 64;
    if (t == 0) anyf = 0;
    __syncthreads();
    if (t < 64 && flags[rbase + t]) anyf = 1;
    __syncthreads();
    if (!anyf) return;
    for (int r = 0; r < 64; ++r) {
        if (!flags[rbase + r]) continue;
        const int n = rbase + r;
        const float sz = s_z[n];
        const float4* zr = (const float4*)(Z + (size_t)n * D);
        float bd = 1e30f; int bk = 0x7FFFFFFF;
        for (int k = t; k < K; k += 256) {
            const float4* wr = (const float4*)(W + (size_t)k * D);
            float ax = 0.f, ay = 0.f, az = 0.f, aw = 0.f;
            for (int qq = 0; qq < 64; ++qq) {
                float4 zv = zr[qq], wv = wr[qq];
                ax = fmaf(zv.x, wv.x, ax);
                ay = fmaf(zv.y, wv.y, ay);
                az = fmaf(zv.z, wv.z, az);
                aw = fmaf(zv.w, wv.w, aw);
            }
            float dd = (sz + s_w[k]) - 2.0f * ((ax + ay) + (az + aw));
            if (dd < bd || (dd == bd && k < bk)) { bd = dd; bk = k; }
        }
        atomicMin(&best[n], ((unsigned long long)encf(bd) << 32) | (unsigned)bk);
    }
}

// ----------------------------------------------------------- outputs -------
__global__ __launch_bounds__(256) void out_kernel(const float* __restrict__ W,
                                                  const unsigned long long* __restrict__ best,
                                                  float* __restrict__ zq,
                                                  float* __restrict__ idx_f,
                                                  float* __restrict__ loss) {
    const int w = threadIdx.x >> 6, lane = threadIdx.x & 63;
#pragma unroll
    for (int i = 0; i < 4; ++i) {
        const int r = blockIdx.x * 16 + w * 4 + i;
        const int k = (int)(unsigned)(best[r] & 0xFFFFFFFFull);
        float4 v = ((const float4*)(W + (size_t)k * D))[lane];
        ((float4*)(zq + (size_t)r * D))[lane] = v;
        if (lane == 0) {
            idx_f[r] = (float)k;
            loss[r] = 0.f;
        }
    }
}

// ------------------------------------------------------------ launch -------
extern "C" void kernel_launch(void* const* d_in, const int* in_sizes, int n_in,
                              void* d_out, int out_size, void* d_ws, size_t ws_size,
                              hipStream_t stream) {
    const float* Z = (const float*)d_in[0];
    const float* W = (const float*)d_in[1];

    float* zq    = (float*)d_out;                                  // [N, D]
    float* idx_f = zq + (size_t)N * D;                             // [N]
    float* loss  = idx_f + N;                                      // [N]

    // bf16 fragment arrays live in the not-yet-written zq region
    short* Zf = (short*)d_out;                                     // 16 MB
    short* Wf = (short*)((char*)d_out + (size_t)16 * 1024 * 1024); // 4 MB

    float* s_w = (float*)d_ws;                                     // 32 KB
    float* s_z = s_w + K;                                          // 128 KB
    unsigned long long* best = (unsigned long long*)(s_z + N);     // 256 KB
    unsigned char* flags = (unsigned char*)(best + N);             // 32 KB

    fuse_pack<<<N / 64, 256, 0, stream>>>(Z, Zf, s_z, best, flags); // + init
    fuse_pack<<<K / 64, 256, 0, stream>>>(W, Wf, s_w, nullptr, nullptr);
    vq_screen<<<512, 256, 0, stream>>>(Zf, Wf, s_w, s_z, Z, W, best, flags);
    vq_fallback<<<N / 64, 256, 0, stream>>>(Z, W, s_z, s_w, flags, best);
    out_kernel<<<N / 16, 256, 0, stream>>>(W, best, zq, idx_f, loss);
}

// Round 7
// 376.981 us; speedup vs baseline: 5.1257x; 5.1257x over previous
//
#include <hip/hip_runtime.h>
#include <stdint.h>

// VectorQuantizer: bf16-MFMA screen (A-in-registers, K-split, warmup-seeded
// margin recording, double-buffered pipelined B staging, LDS+global-spill
// candidate tiers) + exact fp32 rescore.
// Exact semantics (proven R2..R6): d = fl(fl(s_z_pairwise + s_w_pairwise) - 2*dot_f32),
// argmin lowest-index tie-break == global atomicMin on (encf(d)<<32)|k.

constexpr int N = 32768;
constexpr int K = 8192;
constexpr int D = 256;
constexpr int CAP = 12;        // LDS candidate slots per row-quarter
constexpr int SCAP = 20;       // global spill slots per row-quarter (12..31)
constexpr int TCAP = CAP + SCAP;
constexpr int NT = 36;         // 4 warmup tiles + 32 recording tiles
#define MARGIN 1.0e-4f

typedef __attribute__((ext_vector_type(8))) short short8v;
typedef __attribute__((ext_vector_type(4))) float float4v;

__device__ inline short f2bf(float f) {            // RNE float->bf16
    unsigned u = __float_as_uint(f);
    unsigned r = (u + 0x7FFFu + ((u >> 16) & 1u)) >> 16;
    return (short)r;
}
__device__ inline unsigned encf(float x) {         // order-preserving f32->u32
    unsigned u = __float_as_uint(x);
    return (u & 0x80000000u) ? ~u : (u | 0x80000000u);
}
__device__ inline float decf(unsigned e) {
    unsigned u = (e & 0x80000000u) ? (e & 0x7FFFFFFFu) : ~e;
    return __uint_as_float(u);
}
__device__ inline void load_lds16(const void* g, void* l) {
    __builtin_amdgcn_global_load_lds(
        (const __attribute__((address_space(1))) void*)g,
        (__attribute__((address_space(3))) void*)l, 16, 0, 0);
}

// ---------------------------------------------- fused repack + rowsq -------
__global__ __launch_bounds__(256) void fuse_pack(const float* __restrict__ X,
                                                 short* __restrict__ Xf,
                                                 float* __restrict__ s_out,
                                                 unsigned long long* __restrict__ best,
                                                 unsigned char* __restrict__ flags) {
    __shared__ float raw[64][260];
    __shared__ float hres[64][2];
    const int t = threadIdx.x;
    const size_t base = (size_t)blockIdx.x * 64 * D;
#pragma unroll
    for (int it = 0; it < 16; ++it) {
        int idx = it * 256 + t;
        int r = idx >> 6, c = idx & 63;
        float4 v = ((const float4*)(X + base))[idx];
        *(float4*)&raw[r][c * 4] = v;
    }
    __syncthreads();
    if (t < 128) {                     // half-row pairwise sum (order == R2, PROVEN)
        const int row = t >> 1, h = t & 1;
        const float* ph = raw[row] + h * 128;
        float r8[8];
#pragma unroll
        for (int j = 0; j < 8; ++j) r8[j] = __fmul_rn(ph[j], ph[j]);
        for (int i = 8; i < 128; i += 8)
#pragma unroll
            for (int j = 0; j < 8; ++j)
                r8[j] = __fadd_rn(r8[j], __fmul_rn(ph[i + j], ph[i + j]));
        hres[row][h] = __fadd_rn(__fadd_rn(__fadd_rn(r8[0], r8[1]), __fadd_rn(r8[2], r8[3])),
                                 __fadd_rn(__fadd_rn(r8[4], r8[5]), __fadd_rn(r8[6], r8[7])));
    }
    // bf16 MFMA-fragment repack
    {
        const int lane = t & 63, w = t >> 6, l4 = lane >> 4, l15 = lane & 15;
        const int row = w * 16 + l15;
#pragma unroll
        for (int s = 0; s < 8; ++s) {
            const float* src = &raw[row][s * 32 + l4 * 8];
            float4 v0 = *(const float4*)src;
            float4 v1 = *(const float4*)(src + 4);
            short8v o;
            o[0] = f2bf(v0.x); o[1] = f2bf(v0.y); o[2] = f2bf(v0.z); o[3] = f2bf(v0.w);
            o[4] = f2bf(v1.x); o[5] = f2bf(v1.y); o[6] = f2bf(v1.z); o[7] = f2bf(v1.w);
            *(short8v*)(Xf + ((size_t)(blockIdx.x * 4 + w) * 8 + s) * 512 + lane * 8) = o;
        }
    }
    __syncthreads();
    if (t < 64) {
        s_out[blockIdx.x * 64 + t] = __fadd_rn(hres[t][0], hres[t][1]);
        if (best) {
            best[blockIdx.x * 64 + t] = 0xFFFFFFFFFFFFFFFFull;
            flags[blockIdx.x * 64 + t] = 0;
        }
    }
}

// ------------------------------------------------------------- screen ------
// grid 512 = 128 row-groups x 4 K-quarters. Block: 4 waves; wave w owns rows
// n0+w*64 (A frags in 128 VGPR). B: 64-col tiles, double-buffered
// global_load_lds pipeline. Candidates: 12 LDS slots + 20 global spill slots
// per row-quarter (block-local; __threadfence_block + barrier before rescore).
__global__ __launch_bounds__(256, 2) void vq_screen(
    const short* __restrict__ Zf, const short* __restrict__ Wf,
    const float* __restrict__ s_w, const float* __restrict__ s_z,
    const float* __restrict__ Z, const float* __restrict__ W,
    unsigned* __restrict__ spill,
    unsigned long long* __restrict__ best, unsigned char* __restrict__ gflags)
{
    __shared__ short Bs[2][4][8][512];       // 64 KB double buffer
    __shared__ unsigned rowmax[256];         // 1 KB
    __shared__ unsigned ccnt[256];           // 1 KB
    __shared__ unsigned candkm[256][CAP];    // 12 KB  (encf(m)&0xFFFF0000)|k

    const int t = threadIdx.x, w = t >> 6, lane = t & 63;
    const int l4 = lane >> 4, l15 = lane & 15;
    const int q = blockIdx.x & 3, rg = blockIdx.x >> 2;
    const int n0 = rg * 256;
    const int kq0 = q * 2048;
    unsigned* const spillB = spill + (size_t)blockIdx.x * 256 * SCAP;

    rowmax[t] = encf(-1e30f);
    ccnt[t] = 0u;

    short8v af[4][8];
    {
        const int R = (n0 >> 4) + w * 4;
#pragma unroll
        for (int g = 0; g < 4; ++g)
#pragma unroll
            for (int s = 0; s < 8; ++s)
                af[g][s] = *(const short8v*)(Zf + ((size_t)(R + g) * 8 + s) * 512 + lane * 8);
    }

    float maxv[16];
#pragma unroll
    for (int i = 0; i < 16; ++i) maxv[i] = -1e30f;

    // prologue: stage tile 0 into buffer 0 (wave w stages col16-group w)
    {
        const int col16 = (kq0 >> 4) + w;
        const short* gB = Wf + (size_t)col16 * 8 * 512 + lane * 8;
#pragma unroll
        for (int s = 0; s < 8; ++s)
            load_lds16(gB + s * 512, &Bs[0][w][s][0]);
    }

    for (int tt = 0; tt < NT; ++tt) {
        const int cur = tt & 1;
        __syncthreads();                     // drains own stage(tt); waves synced
        if (tt + 1 < NT) {                   // prefetch tile tt+1
            const int ktn = (tt + 1 < 4) ? (tt + 1) : (tt + 1 - 4);
            const int col16 = (kq0 >> 4) + ktn * 4 + w;
            const short* gB = Wf + (size_t)col16 * 8 * 512 + lane * 8;
#pragma unroll
            for (int s = 0; s < 8; ++s)
                load_lds16(gB + s * 512, &Bs[cur ^ 1][w][s][0]);
        }

        float4v acc[4][4];
#pragma unroll
        for (int i = 0; i < 4; ++i)
#pragma unroll
            for (int j = 0; j < 4; ++j)
#pragma unroll
                for (int r = 0; r < 4; ++r) acc[i][j][r] = 0.f;

#pragma unroll
        for (int s = 0; s < 8; ++s) {
            short8v bf[4];
#pragma unroll
            for (int j = 0; j < 4; ++j)
                bf[j] = *(const short8v*)&Bs[cur][j][s][lane * 8];
#pragma unroll
            for (int i = 0; i < 4; ++i)
#pragma unroll
                for (int j = 0; j < 4; ++j)
                    acc[i][j] = __builtin_amdgcn_mfma_f32_16x16x32_bf16(af[i][s], bf[j], acc[i][j], 0, 0, 0);
        }

        if (tt < 4) {                        // warmup: seed row max only
#pragma unroll
            for (int i = 0; i < 4; ++i)
#pragma unroll
                for (int r = 0; r < 4; ++r) {
                    const int slot = i * 4 + r;
                    float mj = fmaxf(fmaxf(acc[i][0][r], acc[i][1][r]),
                                     fmaxf(acc[i][2][r], acc[i][3][r]));
                    if (mj > maxv[slot]) {
                        maxv[slot] = mj;
                        atomicMax(&rowmax[w * 64 + i * 16 + l4 * 4 + r], encf(mj));
                    }
                }
            continue;
        }

        // recording tile: refresh bound, then record into LDS or spill tier
        const int kt = tt - 4;
#pragma unroll
        for (int i = 0; i < 4; ++i) {
            uint4 rm = *(const uint4*)&rowmax[w * 64 + i * 16 + l4 * 4];
            maxv[i * 4 + 0] = fmaxf(maxv[i * 4 + 0], decf(rm.x));
            maxv[i * 4 + 1] = fmaxf(maxv[i * 4 + 1], decf(rm.y));
            maxv[i * 4 + 2] = fmaxf(maxv[i * 4 + 2], decf(rm.z));
            maxv[i * 4 + 3] = fmaxf(maxv[i * 4 + 3], decf(rm.w));
        }
        const int kb = kq0 + kt * 64 + l15;
#pragma unroll
        for (int i = 0; i < 4; ++i) {
#pragma unroll
            for (int r = 0; r < 4; ++r) {
                const int slot = i * 4 + r;
                const int rowL = w * 64 + i * 16 + l4 * 4 + r;
                float v0 = acc[i][0][r], v1 = acc[i][1][r];
                float v2 = acc[i][2][r], v3 = acc[i][3][r];
                float mj = fmaxf(fmaxf(v0, v1), fmaxf(v2, v3));
                if (mj > maxv[slot]) {
                    maxv[slot] = mj;
                    atomicMax(&rowmax[rowL], encf(mj));
                }
                float th = maxv[slot] - MARGIN;
                if (mj >= th) {
                    float vv[4] = {v0, v1, v2, v3};
#pragma unroll
                    for (int j = 0; j < 4; ++j) {
                        if (vv[j] >= th) {
                            unsigned c = atomicAdd(&ccnt[rowL], 1u);
                            unsigned pk = (encf(vv[j]) & 0xFFFF0000u) | (unsigned)(kb + 16 * j);
                            if (c < CAP) candkm[rowL][c] = pk;
                            else if (c < TCAP) spillB[rowL * SCAP + (c - CAP)] = pk;
                        }
                    }
                }
            }
        }
    }

    __threadfence_block();                   // spill stores visible in-block
    __syncthreads();
    // exact fp32 rescore of non-stale survivors; submit via global atomicMin
    {
        const int n = n0 + t;
        unsigned cnt = ccnt[t];
        if (cnt > (unsigned)TCAP) {
            gflags[n] = 1;                   // overflow -> full-row fallback (P~1e-13)
        } else if (cnt > 0) {
            const float thr = decf(rowmax[t]) - MARGIN;
            const float sz = s_z[n];
            const float4* zr = (const float4*)(Z + (size_t)n * D);
            float bd = 1e30f; int bk = 0x7FFFFFFF;
            for (unsigned c = 0; c < cnt; ++c) {
                const unsigned cm = (c < CAP) ? candkm[t][c] : spillB[t * SCAP + (c - CAP)];
                if (decf((cm & 0xFFFF0000u) + 0x10000u) < thr) continue;  // surely stale
                const int k = (int)(cm & 0x1FFFu);
                const float4* wr = (const float4*)(W + (size_t)k * D);
                float ax = 0.f, ay = 0.f, az = 0.f, aw = 0.f;
                for (int qq = 0; qq < 64; ++qq) {
                    float4 zv = zr[qq], wv = wr[qq];
                    ax = fmaf(zv.x, wv.x, ax);
                    ay = fmaf(zv.y, wv.y, ay);
                    az = fmaf(zv.z, wv.z, az);
                    aw = fmaf(zv.w, wv.w, aw);
                }
                float dot = (ax + ay) + (az + aw);
                float dd = (sz + s_w[k]) - 2.0f * dot;
                if (dd < bd || (dd == bd && k < bk)) { bd = dd; bk = k; }
            }
            atomicMin(&best[n], ((unsigned long long)encf(bd) << 32) | (unsigned)bk);
        }
    }
}

// ------------------------------------------------------------ fallback -----
__global__ __launch_bounds__(256) void vq_fallback(
    const float* __restrict__ Z, const float* __restrict__ W,
    const float* __restrict__ s_z, const float* __restrict__ s_w,
    const unsigned char* __restrict__ flags, unsigned long long* __restrict__ best)
{
    __shared__ int anyf;
    const int t = threadIdx.x;
    const int rbase = blockIdx.x * 64;
    if (t == 0) anyf = 0;
    __syncthreads();
    if (t < 64 && flags[rbase + t]) anyf = 1;
    __syncthreads();
    if (!anyf) return;
    for (int r = 0; r < 64; ++r) {
        if (!flags[rbase + r]) continue;
        const int n = rbase + r;
        const float sz = s_z[n];
        const float4* zr = (const float4*)(Z + (size_t)n * D);
        float bd = 1e30f; int bk = 0x7FFFFFFF;
        for (int k = t; k < K; k += 256) {
            const float4* wr = (const float4*)(W + (size_t)k * D);
            float ax = 0.f, ay = 0.f, az = 0.f, aw = 0.f;
            for (int qq = 0; qq < 64; ++qq) {
                float4 zv = zr[qq], wv = wr[qq];
                ax = fmaf(zv.x, wv.x, ax);
                ay = fmaf(zv.y, wv.y, ay);
                az = fmaf(zv.z, wv.z, az);
                aw = fmaf(zv.w, wv.w, aw);
            }
            float dd = (sz + s_w[k]) - 2.0f * ((ax + ay) + (az + aw));
            if (dd < bd || (dd == bd && k < bk)) { bd = dd; bk = k; }
        }
        atomicMin(&best[n], ((unsigned long long)encf(bd) << 32) | (unsigned)bk);
    }
}

// ----------------------------------------------------------- outputs -------
__global__ __launch_bounds__(256) void out_kernel(const float* __restrict__ W,
                                                  const unsigned long long* __restrict__ best,
                                                  float* __restrict__ zq,
                                                  float* __restrict__ idx_f,
                                                  float* __restrict__ loss) {
    const int w = threadIdx.x >> 6, lane = threadIdx.x & 63;
#pragma unroll
    for (int i = 0; i < 4; ++i) {
        const int r = blockIdx.x * 16 + w * 4 + i;
        const int k = (int)(unsigned)(best[r] & 0xFFFFFFFFull);
        float4 v = ((const float4*)(W + (size_t)k * D))[lane];
        ((float4*)(zq + (size_t)r * D))[lane] = v;
        if (lane == 0) {
            idx_f[r] = (float)k;
            loss[r] = 0.f;
        }
    }
}

// ------------------------------------------------------------ launch -------
extern "C" void kernel_launch(void* const* d_in, const int* in_sizes, int n_in,
                              void* d_out, int out_size, void* d_ws, size_t ws_size,
                              hipStream_t stream) {
    const float* Z = (const float*)d_in[0];
    const float* W = (const float*)d_in[1];

    float* zq    = (float*)d_out;                                  // [N, D]
    float* idx_f = zq + (size_t)N * D;                             // [N]
    float* loss  = idx_f + N;                                      // [N]

    // zq region (33.5 MB) reused as scratch until out_kernel:
    short* Zf = (short*)d_out;                                     // [0, 16 MB)
    short* Wf = (short*)((char*)d_out + (size_t)16 * 1024 * 1024); // [16, 20 MB)
    unsigned* spill = (unsigned*)((char*)d_out + (size_t)20 * 1024 * 1024); // [20, 30 MB)

    float* s_w = (float*)d_ws;                                     // 32 KB
    float* s_z = s_w + K;                                          // 128 KB
    unsigned long long* best = (unsigned long long*)(s_z + N);     // 256 KB
    unsigned char* flags = (unsigned char*)(best + N);             // 32 KB

    fuse_pack<<<N / 64, 256, 0, stream>>>(Z, Zf, s_z, best, flags); // + init
    fuse_pack<<<K / 64, 256, 0, stream>>>(W, Wf, s_w, nullptr, nullptr);
    vq_screen<<<512, 256, 0, stream>>>(Zf, Wf, s_w, s_z, Z, W, spill, best, flags);
    vq_fallback<<<N / 64, 256, 0, stream>>>(Z, W, s_z, s_w, flags, best);
    out_kernel<<<N / 16, 256, 0, stream>>>(W, best, zq, idx_f, loss);
}

// Round 8
// 349.405 us; speedup vs baseline: 5.5302x; 1.0789x over previous
//
#include <hip/hip_runtime.h>
#include <stdint.h>

// VectorQuantizer: bf16-MFMA screen (A-in-LDS shared, B streamed from L2 into
// registers, barrier-free K-loop, warmup-seeded margin recording, LDS+spill
// candidate tiers) + exact fp32 rescore.
// Exact semantics (proven R2..R7): d = fl(fl(s_z_pairwise + s_w_pairwise) - 2*dot_f32),
// argmin lowest-index tie-break == global atomicMin on (encf(d)<<32)|k.

constexpr int N = 32768;
constexpr int K = 8192;
constexpr int D = 256;
constexpr int CAP = 16;        // LDS candidate slots per row (per block)
constexpr int SCAP = 16;       // global spill slots per row (per block)
constexpr int TCAP = CAP + SCAP;
#define MARGIN 1.0e-4f

typedef __attribute__((ext_vector_type(8))) short short8v;
typedef __attribute__((ext_vector_type(4))) float float4v;

__device__ inline short f2bf(float f) {            // RNE float->bf16
    unsigned u = __float_as_uint(f);
    unsigned r = (u + 0x7FFFu + ((u >> 16) & 1u)) >> 16;
    return (short)r;
}
__device__ inline unsigned encf(float x) {         // order-preserving f32->u32
    unsigned u = __float_as_uint(x);
    return (u & 0x80000000u) ? ~u : (u | 0x80000000u);
}
__device__ inline float decf(unsigned e) {
    unsigned u = (e & 0x80000000u) ? (e & 0x7FFFFFFFu) : ~e;
    return __uint_as_float(u);
}
__device__ inline void load_lds16(const void* g, void* l) {
    __builtin_amdgcn_global_load_lds(
        (const __attribute__((address_space(1))) void*)g,
        (__attribute__((address_space(3))) void*)l, 16, 0, 0);
}

// ---------------------------------------------- fused repack + rowsq -------
__global__ __launch_bounds__(256) void fuse_pack(const float* __restrict__ X,
                                                 short* __restrict__ Xf,
                                                 float* __restrict__ s_out,
                                                 unsigned long long* __restrict__ best,
                                                 unsigned char* __restrict__ flags) {
    __shared__ float raw[64][260];
    __shared__ float hres[64][2];
    const int t = threadIdx.x;
    const size_t base = (size_t)blockIdx.x * 64 * D;
#pragma unroll
    for (int it = 0; it < 16; ++it) {
        int idx = it * 256 + t;
        int r = idx >> 6, c = idx & 63;
        float4 v = ((const float4*)(X + base))[idx];
        *(float4*)&raw[r][c * 4] = v;
    }
    __syncthreads();
    if (t < 128) {                     // half-row pairwise sum (order == R2, PROVEN)
        const int row = t >> 1, h = t & 1;
        const float* ph = raw[row] + h * 128;
        float r8[8];
#pragma unroll
        for (int j = 0; j < 8; ++j) r8[j] = __fmul_rn(ph[j], ph[j]);
        for (int i = 8; i < 128; i += 8)
#pragma unroll
            for (int j = 0; j < 8; ++j)
                r8[j] = __fadd_rn(r8[j], __fmul_rn(ph[i + j], ph[i + j]));
        hres[row][h] = __fadd_rn(__fadd_rn(__fadd_rn(r8[0], r8[1]), __fadd_rn(r8[2], r8[3])),
                                 __fadd_rn(__fadd_rn(r8[4], r8[5]), __fadd_rn(r8[6], r8[7])));
    }
    // bf16 MFMA-fragment repack
    {
        const int lane = t & 63, w = t >> 6, l4 = lane >> 4, l15 = lane & 15;
        const int row = w * 16 + l15;
#pragma unroll
        for (int s = 0; s < 8; ++s) {
            const float* src = &raw[row][s * 32 + l4 * 8];
            float4 v0 = *(const float4*)src;
            float4 v1 = *(const float4*)(src + 4);
            short8v o;
            o[0] = f2bf(v0.x); o[1] = f2bf(v0.y); o[2] = f2bf(v0.z); o[3] = f2bf(v0.w);
            o[4] = f2bf(v1.x); o[5] = f2bf(v1.y); o[6] = f2bf(v1.z); o[7] = f2bf(v1.w);
            *(short8v*)(Xf + ((size_t)(blockIdx.x * 4 + w) * 8 + s) * 512 + lane * 8) = o;
        }
    }
    __syncthreads();
    if (t < 64) {
        s_out[blockIdx.x * 64 + t] = __fadd_rn(hres[t][0], hres[t][1]);
        if (best) {
            best[blockIdx.x * 64 + t] = 0xFFFFFFFFFFFFFFFFull;
            flags[blockIdx.x * 64 + t] = 0;
        }
    }
}

// ------------------------------------------------------------- screen ------
// grid 1024 = 512 row-groups (64 rows) x 2 K-halves. Block: 4 waves share the
// 64-row A tile in LDS; wave w privately scans cols [half*4096 + w*1024, +1024)
// = 16 tiles of 64 cols. B fragments load straight from L2 (Wf) to registers,
// ping-ponged against MFMA. NO barriers in the K-loop. Candidates pooled per
// row in LDS (CAP) + global spill (SCAP); tile 0 re-scanned after a max-only
// warmup so the shared row bound is seeded from 4x64=256 cols.
__global__ __launch_bounds__(256, 3) void vq_screen(
    const short* __restrict__ Zf, const short* __restrict__ Wf,
    const float* __restrict__ s_w, const float* __restrict__ s_z,
    const float* __restrict__ Z, const float* __restrict__ W,
    unsigned* __restrict__ spill,
    unsigned long long* __restrict__ best, unsigned char* __restrict__ gflags)
{
    __shared__ short As[4][8][512];          // 32 KB: 64-row A tile
    __shared__ unsigned rowmax[64];          // encoded running row max (shared)
    __shared__ unsigned ccnt[64];
    __shared__ unsigned candkm[64][CAP];     // (encf(m)&0xFFFF0000)|k

    const int t = threadIdx.x, w = t >> 6, lane = t & 63;
    const int l4 = lane >> 4, l15 = lane & 15;
    const int rg = blockIdx.x >> 1;          // 64-row group
    const int hh = blockIdx.x & 1;           // K half
    const int n0 = rg * 64;
    const int kw0 = hh * 4096 + w * 1024;    // this wave's col base
    unsigned* const spillB = spill + (size_t)blockIdx.x * 64 * SCAP;

    if (t < 64) { rowmax[t] = encf(-1e30f); ccnt[t] = 0u; }
    {   // stage A once: wave w stages row16-group w
        const short* gA = Zf + ((size_t)(rg * 4 + w) * 8) * 512 + lane * 8;
#pragma unroll
        for (int s = 0; s < 8; ++s)
            load_lds16(gA + s * 512, &As[w][s][0]);
    }
    __syncthreads();                         // vmcnt(0) drain: A + inits visible

    float maxv[16];
#pragma unroll
    for (int i = 0; i < 16; ++i) maxv[i] = -1e30f;

    for (int tt = 0; tt < 17; ++tt) {        // tt=0: warmup re-scan of tile 0
        const int ttc = (tt == 0) ? 0 : (tt - 1);
        const int c16base = (kw0 >> 4) + ttc * 4;
        const short* bbase = Wf + lane * 8;

        short8v bfA[4], bfB[4];
#pragma unroll
        for (int j = 0; j < 4; ++j)
            bfA[j] = *(const short8v*)(bbase + ((size_t)(c16base + j) * 8 + 0) * 512);

        float4v acc[4][4];
#pragma unroll
        for (int i = 0; i < 4; ++i)
#pragma unroll
            for (int j = 0; j < 4; ++j)
#pragma unroll
                for (int r = 0; r < 4; ++r) acc[i][j][r] = 0.f;

#pragma unroll
        for (int s = 0; s < 8; ++s) {
            const short8v* cur = (s & 1) ? bfB : bfA;
            short8v* nxt = (s & 1) ? bfA : bfB;
            if (s < 7) {
#pragma unroll
                for (int j = 0; j < 4; ++j)
                    nxt[j] = *(const short8v*)(bbase + ((size_t)(c16base + j) * 8 + s + 1) * 512);
            }
            short8v af[4];
#pragma unroll
            for (int i = 0; i < 4; ++i)
                af[i] = *(const short8v*)&As[i][s][lane * 8];
#pragma unroll
            for (int i = 0; i < 4; ++i)
#pragma unroll
                for (int j = 0; j < 4; ++j)
                    acc[i][j] = __builtin_amdgcn_mfma_f32_16x16x32_bf16(af[i], cur[j], acc[i][j], 0, 0, 0);
        }

        if (tt == 0) {                       // warmup: seed shared row max only
#pragma unroll
            for (int i = 0; i < 4; ++i)
#pragma unroll
                for (int r = 0; r < 4; ++r) {
                    const int slot = i * 4 + r;
                    float mj = fmaxf(fmaxf(acc[i][0][r], acc[i][1][r]),
                                     fmaxf(acc[i][2][r], acc[i][3][r]));
                    if (mj > maxv[slot]) {
                        maxv[slot] = mj;
                        atomicMax(&rowmax[i * 16 + l4 * 4 + r], encf(mj));
                    }
                }
            continue;
        }

        // recording tile: refresh bound from pooled rowmax, then record
#pragma unroll
        for (int i = 0; i < 4; ++i) {
            uint4 rm = *(const uint4*)&rowmax[i * 16 + l4 * 4];
            maxv[i * 4 + 0] = fmaxf(maxv[i * 4 + 0], decf(rm.x));
            maxv[i * 4 + 1] = fmaxf(maxv[i * 4 + 1], decf(rm.y));
            maxv[i * 4 + 2] = fmaxf(maxv[i * 4 + 2], decf(rm.z));
            maxv[i * 4 + 3] = fmaxf(maxv[i * 4 + 3], decf(rm.w));
        }
        const int kb = kw0 + ttc * 64 + l15;
#pragma unroll
        for (int i = 0; i < 4; ++i) {
#pragma unroll
            for (int r = 0; r < 4; ++r) {
                const int slot = i * 4 + r;
                const int rowL = i * 16 + l4 * 4 + r;
                float v0 = acc[i][0][r], v1 = acc[i][1][r];
                float v2 = acc[i][2][r], v3 = acc[i][3][r];
                float mj = fmaxf(fmaxf(v0, v1), fmaxf(v2, v3));
                if (mj > maxv[slot]) {
                    maxv[slot] = mj;
                    atomicMax(&rowmax[rowL], encf(mj));
                }
                float th = maxv[slot] - MARGIN;
                if (mj >= th) {
                    float vv[4] = {v0, v1, v2, v3};
#pragma unroll
                    for (int j = 0; j < 4; ++j) {
                        if (vv[j] >= th) {
                            unsigned c = atomicAdd(&ccnt[rowL], 1u);
                            unsigned pk = (encf(vv[j]) & 0xFFFF0000u) | (unsigned)(kb + 16 * j);
                            if (c < CAP) candkm[rowL][c] = pk;
                            else if (c < TCAP) spillB[rowL * SCAP + (c - CAP)] = pk;
                        }
                    }
                }
            }
        }
    }

    __threadfence_block();                   // spill stores visible in-block
    __syncthreads();
    // exact fp32 rescore (R2-proven formula): 4 threads per row, stride-4 cands
    {
        const int row = t & 63, part = t >> 6;
        const int n = n0 + row;
        unsigned cnt = ccnt[row];
        if (cnt > (unsigned)TCAP) {
            if (part == 0) gflags[n] = 1;    // overflow -> full-row fallback
        } else if (cnt > 0) {
            const float thr = decf(rowmax[row]) - MARGIN;
            const float sz = s_z[n];
            const float4* zr = (const float4*)(Z + (size_t)n * D);
            float bd = 1e30f; int bk = 0x7FFFFFFF;
            for (unsigned c = part; c < cnt; c += 4) {
                const unsigned cm = (c < CAP) ? candkm[row][c] : spillB[row * SCAP + (c - CAP)];
                if (decf((cm & 0xFFFF0000u) + 0x10000u) < thr) continue;  // surely stale
                const int k = (int)(cm & 0x1FFFu);
                const float4* wr = (const float4*)(W + (size_t)k * D);
                float ax = 0.f, ay = 0.f, az = 0.f, aw = 0.f;
                for (int qq = 0; qq < 64; ++qq) {
                    float4 zv = zr[qq], wv = wr[qq];
                    ax = fmaf(zv.x, wv.x, ax);
                    ay = fmaf(zv.y, wv.y, ay);
                    az = fmaf(zv.z, wv.z, az);
                    aw = fmaf(zv.w, wv.w, aw);
                }
                float dot = (ax + ay) + (az + aw);
                float dd = (sz + s_w[k]) - 2.0f * dot;
                if (dd < bd || (dd == bd && k < bk)) { bd = dd; bk = k; }
            }
            if (bk != 0x7FFFFFFF)
                atomicMin(&best[n], ((unsigned long long)encf(bd) << 32) | (unsigned)bk);
        }
    }
}

// ------------------------------------------------------------ fallback -----
__global__ __launch_bounds__(256) void vq_fallback(
    const float* __restrict__ Z, const float* __restrict__ W,
    const float* __restrict__ s_z, const float* __restrict__ s_w,
    const unsigned char* __restrict__ flags, unsigned long long* __restrict__ best)
{
    __shared__ int anyf;
    const int t = threadIdx.x;
    const int rbase = blockIdx.x * 64;
    if (t == 0) anyf = 0;
    __syncthreads();
    if (t < 64 && flags[rbase + t]) anyf = 1;
    __syncthreads();
    if (!anyf) return;
    for (int r = 0; r < 64; ++r) {
        if (!flags[rbase + r]) continue;
        const int n = rbase + r;
        const float sz = s_z[n];
        const float4* zr = (const float4*)(Z + (size_t)n * D);
        float bd = 1e30f; int bk = 0x7FFFFFFF;
        for (int k = t; k < K; k += 256) {
            const float4* wr = (const float4*)(W + (size_t)k * D);
            float ax = 0.f, ay = 0.f, az = 0.f, aw = 0.f;
            for (int qq = 0; qq < 64; ++qq) {
                float4 zv = zr[qq], wv = wr[qq];
                ax = fmaf(zv.x, wv.x, ax);
                ay = fmaf(zv.y, wv.y, ay);
                az = fmaf(zv.z, wv.z, az);
                aw = fmaf(zv.w, wv.w, aw);
            }
            float dd = (sz + s_w[k]) - 2.0f * ((ax + ay) + (az + aw));
            if (dd < bd || (dd == bd && k < bk)) { bd = dd; bk = k; }
        }
        atomicMin(&best[n], ((unsigned long long)encf(bd) << 32) | (unsigned)bk);
    }
}

// ----------------------------------------------------------- outputs -------
__global__ __launch_bounds__(256) void out_kernel(const float* __restrict__ W,
                                                  const unsigned long long* __restrict__ best,
                                                  float* __restrict__ zq,
                                                  float* __restrict__ idx_f,
                                                  float* __restrict__ loss) {
    const int w = threadIdx.x >> 6, lane = threadIdx.x & 63;
#pragma unroll
    for (int i = 0; i < 4; ++i) {
        const int r = blockIdx.x * 16 + w * 4 + i;
        const int k = (int)(unsigned)(best[r] & 0xFFFFFFFFull);
        float4 v = ((const float4*)(W + (size_t)k * D))[lane];
        ((float4*)(zq + (size_t)r * D))[lane] = v;
        if (lane == 0) {
            idx_f[r] = (float)k;
            loss[r] = 0.f;
        }
    }
}

// ------------------------------------------------------------ launch -------
extern "C" void kernel_launch(void* const* d_in, const int* in_sizes, int n_in,
                              void* d_out, int out_size, void* d_ws, size_t ws_size,
                              hipStream_t stream) {
    const float* Z = (const float*)d_in[0];
    const float* W = (const float*)d_in[1];

    float* zq    = (float*)d_out;                                  // [N, D]
    float* idx_f = zq + (size_t)N * D;                             // [N]
    float* loss  = idx_f + N;                                      // [N]

    // zq region (33.5 MB) reused as scratch until out_kernel:
    short* Zf = (short*)d_out;                                     // [0, 16 MB)
    short* Wf = (short*)((char*)d_out + (size_t)16 * 1024 * 1024); // [16, 20 MB)
    unsigned* spill = (unsigned*)((char*)d_out + (size_t)20 * 1024 * 1024); // [20, 24.2 MB)

    float* s_w = (float*)d_ws;                                     // 32 KB
    float* s_z = s_w + K;                                          // 128 KB
    unsigned long long* best = (unsigned long long*)(s_z + N);     // 256 KB
    unsigned char* flags = (unsigned char*)(best + N);             // 32 KB

    fuse_pack<<<N / 64, 256, 0, stream>>>(Z, Zf, s_z, best, flags); // + init
    fuse_pack<<<K / 64, 256, 0, stream>>>(W, Wf, s_w, nullptr, nullptr);
    vq_screen<<<1024, 256, 0, stream>>>(Zf, Wf, s_w, s_z, Z, W, spill, best, flags);
    vq_fallback<<<N / 64, 256, 0, stream>>>(Z, W, s_z, s_w, flags, best);
    out_kernel<<<N / 16, 256, 0, stream>>>(W, best, zq, idx_f, loss);
}